// Round 5
// baseline (61.837 us; speedup 1.0000x reference)
//
#include <hip/hip_runtime.h>
#include <hip/hip_bf16.h>

#define B_ 8
#define N_ 16384
#define S_ 1024
#define K_ 32
#define CSTEM 64
#define CPATCH 128
#define INDIM 91
#define LDA 104   // LDS row stride (bf16) for A tile
#define LDH 136   // LDS row stride (bf16) for h1 tile
#define PPB 4     // patches per block

typedef __attribute__((ext_vector_type(8))) short short8v;  // 8 bf16 = 4 VGPRs
typedef __attribute__((ext_vector_type(4))) float f32x4;

static __device__ __forceinline__ unsigned short f2bf(float f) {
  union { float f; unsigned int u; } v; v.f = f;
  return (unsigned short)((v.u + 0x7FFFu + ((v.u >> 16) & 1u)) >> 16);  // RNE
}

// -------- Kernel 0: pack w1/w2 into MFMA B-fragment order (bf16) --------
__global__ __launch_bounds__(256) void pack_weights(
    const float* __restrict__ w1, const float* __restrict__ w2,
    unsigned short* __restrict__ w1p, unsigned short* __restrict__ w2p)
{
  const int id = blockIdx.x * 256 + threadIdx.x;
  if (id < 3 * 8 * 64) {                       // w1: K padded 91->96 (3 ksteps)
    const int l = id & 63, ct = (id >> 6) & 7, ks = id >> 9;
    const int col = 16 * ct + (l & 15);
    const int kb = 32 * ks + (l >> 4) * 8;
    unsigned short v[8];
    #pragma unroll
    for (int j = 0; j < 8; ++j) {
      const int k = kb + j;
      v[j] = (k < INDIM) ? f2bf(w1[k * CPATCH + col]) : (unsigned short)0;
    }
    *(short8v*)&w1p[(size_t)id * 8] = *(const short8v*)v;
  } else if (id < 3 * 8 * 64 + 4 * 8 * 64) {   // w2: 4 ksteps
    const int id2 = id - 3 * 8 * 64;
    const int l = id2 & 63, ct = (id2 >> 6) & 7, ks = id2 >> 9;
    const int col = 16 * ct + (l & 15);
    const int kb = 32 * ks + (l >> 4) * 8;
    unsigned short v[8];
    #pragma unroll
    for (int j = 0; j < 8; ++j) v[j] = f2bf(w2[(kb + j) * CPATCH + col]);
    *(short8v*)&w2p[(size_t)id2 * 8] = *(const short8v*)v;
  }
}

// -------- Fused kernel: ball query + gather + PE + MFMA MLP + max --------
// One block = PPB patches. Query: 4 waves cooperate, 1024 pts/iter, ordered
// append via per-wave LDS counts + prefix. In-ball coords stashed in LDS at
// discovery (no scattered xyz re-read). Distance math bit-identical to the
// 4x-verified f64-on-f32 expression. MLP identical to verified R4.
__global__ __launch_bounds__(256, 2) void fused_patch(
    const float* __restrict__ xyz, const float* __restrict__ pf,
    const float* __restrict__ pc,
    const unsigned short* __restrict__ w1p, const float* __restrict__ b1,
    const unsigned short* __restrict__ w2p, const float* __restrict__ b2,
    float* __restrict__ idx_out, float* __restrict__ out)
{
  const int tid  = threadIdx.x;
  const int lane = tid & 63;
  const int w    = tid >> 6;

  __shared__ int   sidx[K_];
  __shared__ float sxyz[K_][3];
  __shared__ int   scnt[4];
  __shared__ __align__(16) unsigned short As[K_][LDA];
  __shared__ __align__(16) unsigned short Hs[K_][LDH];

  // Wave-private weight fragments, loaded once, reused for PPB patches.
  short8v w1f[3][2], w2f[4][2];
  #pragma unroll
  for (int ks = 0; ks < 3; ++ks)
    #pragma unroll
    for (int t = 0; t < 2; ++t)
      w1f[ks][t] = *(const short8v*)&w1p[((size_t)(ks * 8 + 2 * w + t) * 64 + lane) * 8];
  #pragma unroll
  for (int ks = 0; ks < 4; ++ks)
    #pragma unroll
    for (int t = 0; t < 2; ++t)
      w2f[ks][t] = *(const short8v*)&w2p[((size_t)(ks * 8 + 2 * w + t) * 64 + lane) * 8];

  const float bias1[2] = { b1[32 * w + (lane & 15)], b1[32 * w + 16 + (lane & 15)] };
  const float bias2[2] = { b2[32 * w + (lane & 15)], b2[32 * w + 16 + (lane & 15)] };

  const unsigned long long lower = (1ull << lane) - 1ull;
  const int off = (w << 8) + (lane << 2);     // this thread's point offset in tile

  for (int p = 0; p < PPB; ++p) {
    const int bs = blockIdx.x * PPB + p;
    const int b  = bs >> 10;                  // S_ = 1024
    const float* __restrict__ xb  = xyz + (size_t)b * N_ * 3;
    const float* __restrict__ pfb = pf  + (size_t)b * N_ * CSTEM;

    const float cen0 = pc[bs * 3 + 0];
    const float cen1 = pc[bs * 3 + 1];
    const float cen2 = pc[bs * 3 + 2];
    const double cx = (double)cen0, cy = (double)cen1, cz = (double)cen2;
    const double rr = 0.2 * 0.2;

    // ---- Ball query: 1024 points per iteration (4 waves x 64 lanes x 4 pts)
    int found = 0;
    for (int base = 0; base < N_; base += 1024) {
      const int i0 = base + off;
      const float4 p0 = *(const float4*)&xb[i0 * 3 + 0];   // x0 y0 z0 x1
      const float4 p1 = *(const float4*)&xb[i0 * 3 + 4];   // y1 z1 x2 y2
      const float4 p2 = *(const float4*)&xb[i0 * 3 + 8];   // z2 x3 y3 z3

      double dx, dy, dz;
      dx = (double)p0.x - cx; dy = (double)p0.y - cy; dz = (double)p0.z - cz;
      const bool in0 = (dx * dx + dy * dy + dz * dz) <= rr;
      dx = (double)p0.w - cx; dy = (double)p1.x - cy; dz = (double)p1.y - cz;
      const bool in1 = (dx * dx + dy * dy + dz * dz) <= rr;
      dx = (double)p1.z - cx; dy = (double)p1.w - cy; dz = (double)p2.x - cz;
      const bool in2 = (dx * dx + dy * dy + dz * dz) <= rr;
      dx = (double)p2.y - cx; dy = (double)p2.z - cy; dz = (double)p2.w - cz;
      const bool in3 = (dx * dx + dy * dy + dz * dz) <= rr;

      const unsigned long long m0 = __ballot(in0);
      const unsigned long long m1 = __ballot(in1);
      const unsigned long long m2 = __ballot(in2);
      const unsigned long long m3 = __ballot(in3);

      if (lane == 0)
        scnt[w] = __popcll(m0) + __popcll(m1) + __popcll(m2) + __popcll(m3);
      __syncthreads();

      int pre = found;                         // block-uniform running total
      #pragma unroll
      for (int v = 0; v < 4; ++v) if (v < w) pre += scnt[v];
      const int tot = scnt[0] + scnt[1] + scnt[2] + scnt[3];

      int pp = pre + __popcll(m0 & lower) + __popcll(m1 & lower)
                   + __popcll(m2 & lower) + __popcll(m3 & lower);
      if (in0) { if (pp < K_) { sidx[pp] = i0;     sxyz[pp][0] = p0.x; sxyz[pp][1] = p0.y; sxyz[pp][2] = p0.z; } ++pp; }
      if (in1) { if (pp < K_) { sidx[pp] = i0 + 1; sxyz[pp][0] = p0.w; sxyz[pp][1] = p1.x; sxyz[pp][2] = p1.y; } ++pp; }
      if (in2) { if (pp < K_) { sidx[pp] = i0 + 2; sxyz[pp][0] = p1.z; sxyz[pp][1] = p1.w; sxyz[pp][2] = p2.x; } ++pp; }
      if (in3) { if (pp < K_) { sidx[pp] = i0 + 3; sxyz[pp][0] = p2.y; sxyz[pp][1] = p2.z; sxyz[pp][2] = p2.w; } }

      found += tot;
      __syncthreads();                         // scnt/sidx hazard before next iter
      if (found >= K_) break;                  // block-uniform
    }

    // ---- Fill (reference: pad with first found; if none, index N-1)
    if (found == 0 && tid == 0) {
      sidx[0] = N_ - 1;
      sxyz[0][0] = xb[(N_ - 1) * 3 + 0];
      sxyz[0][1] = xb[(N_ - 1) * 3 + 1];
      sxyz[0][2] = xb[(N_ - 1) * 3 + 2];
    }
    __syncthreads();
    if (tid > 0 && tid >= found && tid < K_) {
      sidx[tid] = sidx[0];
      sxyz[tid][0] = sxyz[0][0];
      sxyz[tid][1] = sxyz[0][1];
      sxyz[tid][2] = sxyz[0][2];
    }
    __syncthreads();

    if (tid < K_) idx_out[(size_t)bs * K_ + tid] = (float)sidx[tid];

    // ---- Gather phase 1: features -> As[row][0..63] (8 threads per row)
    {
      const int row = tid >> 3, sub = tid & 7;
      const int r = sidx[row];
      const float4 f0 = *(const float4*)&pfb[(size_t)r * CSTEM + sub * 8];
      const float4 f1 = *(const float4*)&pfb[(size_t)r * CSTEM + sub * 8 + 4];
      unsigned short v[8];
      v[0] = f2bf(f0.x); v[1] = f2bf(f0.y); v[2] = f2bf(f0.z); v[3] = f2bf(f0.w);
      v[4] = f2bf(f1.x); v[5] = f2bf(f1.y); v[6] = f2bf(f1.z); v[7] = f2bf(f1.w);
      *(short8v*)&As[row][sub * 8] = *(const short8v*)v;
    }
    // ---- Gather phase 2: rel(3)+PE(24)+pad(5) from stashed coords
    {
      const int row = tid & 31, j = tid >> 5;
      float rel[3];
      rel[0] = sxyz[row][0] - cen0;
      rel[1] = sxyz[row][1] - cen1;
      rel[2] = sxyz[row][2] - cen2;
      #pragma unroll
      for (int cc = 0; cc < 4; ++cc) {
        const int c = 64 + 4 * j + cc;
        float val;
        if (c < 67) val = rel[c - 64];
        else if (c < 91) {
          const int q = c - 67, d = q >> 3, rbit = q & 7, band = rbit & 3;
          const float ang = rel[d] * ((float)(1 << band) * 3.14159265358979323846f);
          val = (rbit < 4) ? sinf(ang) : cosf(ang);
        } else val = 0.f;
        As[row][c] = f2bf(val);
      }
    }
    __syncthreads();

    // ---- Layer 1: 32x96 @ 96x128 (A from LDS, B from registers)
    f32x4 acc[2][2] = {};
    #pragma unroll
    for (int ks = 0; ks < 3; ++ks) {
      const int k0 = ks * 32 + (lane >> 4) * 8;
      const short8v a0 = *(const short8v*)&As[(lane & 15)][k0];
      const short8v a1 = *(const short8v*)&As[16 + (lane & 15)][k0];
      acc[0][0] = __builtin_amdgcn_mfma_f32_16x16x32_bf16(a0, w1f[ks][0], acc[0][0], 0, 0, 0);
      acc[0][1] = __builtin_amdgcn_mfma_f32_16x16x32_bf16(a0, w1f[ks][1], acc[0][1], 0, 0, 0);
      acc[1][0] = __builtin_amdgcn_mfma_f32_16x16x32_bf16(a1, w1f[ks][0], acc[1][0], 0, 0, 0);
      acc[1][1] = __builtin_amdgcn_mfma_f32_16x16x32_bf16(a1, w1f[ks][1], acc[1][1], 0, 0, 0);
    }
    #pragma unroll
    for (int rt = 0; rt < 2; ++rt)
      #pragma unroll
      for (int t = 0; t < 2; ++t)
        #pragma unroll
        for (int reg = 0; reg < 4; ++reg) {
          const float h = fmaxf(acc[rt][t][reg] + bias1[t], 0.f);
          const int row = 16 * rt + (lane >> 4) * 4 + reg;
          const int col = 32 * w + 16 * t + (lane & 15);
          Hs[row][col] = f2bf(h);
        }
    __syncthreads();

    // ---- Layer 2: 32x128 @ 128x128 + max over rows
    f32x4 acc2[2][2] = {};
    #pragma unroll
    for (int ks = 0; ks < 4; ++ks) {
      const int k0 = ks * 32 + (lane >> 4) * 8;
      const short8v a0 = *(const short8v*)&Hs[(lane & 15)][k0];
      const short8v a1 = *(const short8v*)&Hs[16 + (lane & 15)][k0];
      acc2[0][0] = __builtin_amdgcn_mfma_f32_16x16x32_bf16(a0, w2f[ks][0], acc2[0][0], 0, 0, 0);
      acc2[0][1] = __builtin_amdgcn_mfma_f32_16x16x32_bf16(a0, w2f[ks][1], acc2[0][1], 0, 0, 0);
      acc2[1][0] = __builtin_amdgcn_mfma_f32_16x16x32_bf16(a1, w2f[ks][0], acc2[1][0], 0, 0, 0);
      acc2[1][1] = __builtin_amdgcn_mfma_f32_16x16x32_bf16(a1, w2f[ks][1], acc2[1][1], 0, 0, 0);
    }
    float m0 = -3.4e38f, m1 = -3.4e38f;
    #pragma unroll
    for (int rt = 0; rt < 2; ++rt)
      #pragma unroll
      for (int reg = 0; reg < 4; ++reg) {
        m0 = fmaxf(m0, acc2[rt][0][reg]);
        m1 = fmaxf(m1, acc2[rt][1][reg]);
      }
    m0 += bias2[0];
    m1 += bias2[1];
    m0 = fmaxf(m0, __shfl_xor(m0, 16));
    m0 = fmaxf(m0, __shfl_xor(m0, 32));
    m1 = fmaxf(m1, __shfl_xor(m1, 16));
    m1 = fmaxf(m1, __shfl_xor(m1, 32));
    if (lane < 16) {
      out[(size_t)bs * CPATCH + 32 * w + lane]      = m0;
      out[(size_t)bs * CPATCH + 32 * w + 16 + lane] = m1;
    }
    __syncthreads();   // As/Hs/sidx reuse protection before next patch
  }
}

extern "C" void kernel_launch(void* const* d_in, const int* in_sizes, int n_in,
                              void* d_out, int out_size, void* d_ws, size_t ws_size,
                              hipStream_t stream) {
  const float* xyz = (const float*)d_in[0];
  const float* pf  = (const float*)d_in[1];
  const float* pc  = (const float*)d_in[2];
  const float* w1  = (const float*)d_in[3];
  const float* b1  = (const float*)d_in[4];
  const float* w2  = (const float*)d_in[5];
  const float* b2  = (const float*)d_in[6];

  float* out     = (float*)d_out;
  float* idx_out = out + (size_t)B_ * S_ * CPATCH;

  unsigned short* w1p = (unsigned short*)d_ws;
  unsigned short* w2p = w1p + 96 * 128;

  pack_weights<<<14, 256, 0, stream>>>(w1, w2, w1p, w2p);
  fused_patch<<<B_ * S_ / PPB, 256, 0, stream>>>(xyz, pf, pc, w1p, b1, w2p, b2,
                                                 idx_out, out);
}

// Round 6
// 61.633 us; speedup vs baseline: 1.0033x; 1.0033x over previous
//
#include <hip/hip_runtime.h>
#include <hip/hip_bf16.h>

#define B_ 8
#define N_ 16384
#define S_ 1024
#define K_ 32
#define CSTEM 64
#define CPATCH 128
#define INDIM 91
#define LDA 104   // LDS row stride (bf16) for A tile
#define LDH 136   // LDS row stride (bf16) for h1 tile
#define CHUNK 4096  // ball-query chunk: 256 threads x 16 pts, no serial chain

typedef __attribute__((ext_vector_type(8))) short short8v;  // 8 bf16 = 4 VGPRs
typedef __attribute__((ext_vector_type(4))) float f32x4;

static __device__ __forceinline__ unsigned short f2bf(float f) {
  union { float f; unsigned int u; } v; v.f = f;
  return (unsigned short)((v.u + 0x7FFFu + ((v.u >> 16) & 1u)) >> 16);  // RNE
}

// -------- Kernel 0: pack w1/w2 into MFMA B-fragment order (bf16) --------
__global__ __launch_bounds__(256) void pack_weights(
    const float* __restrict__ w1, const float* __restrict__ w2,
    unsigned short* __restrict__ w1p, unsigned short* __restrict__ w2p)
{
  const int id = blockIdx.x * 256 + threadIdx.x;
  if (id < 3 * 8 * 64) {                       // w1: K padded 91->96 (3 ksteps)
    const int l = id & 63, ct = (id >> 6) & 7, ks = id >> 9;
    const int col = 16 * ct + (l & 15);
    const int kb = 32 * ks + (l >> 4) * 8;
    unsigned short v[8];
    #pragma unroll
    for (int j = 0; j < 8; ++j) {
      const int k = kb + j;
      v[j] = (k < INDIM) ? f2bf(w1[k * CPATCH + col]) : (unsigned short)0;
    }
    *(short8v*)&w1p[(size_t)id * 8] = *(const short8v*)v;
  } else if (id < 3 * 8 * 64 + 4 * 8 * 64) {   // w2: 4 ksteps
    const int id2 = id - 3 * 8 * 64;
    const int l = id2 & 63, ct = (id2 >> 6) & 7, ks = id2 >> 9;
    const int col = 16 * ct + (l & 15);
    const int kb = 32 * ks + (l >> 4) * 8;
    unsigned short v[8];
    #pragma unroll
    for (int j = 0; j < 8; ++j) v[j] = f2bf(w2[(kb + j) * CPATCH + col]);
    *(short8v*)&w2p[(size_t)id2 * 8] = *(const short8v*)v;
  }
}

// -------- Fused kernel: chunked ball query + gather + PE + MFMA MLP -------
// One block = one patch. Ball query tests a 4096-pt chunk fully in parallel
// (16 pts/thread -> bitmask), then does an ordered cross-block append via
// shfl prefix + LDS wave sums. <=4 chunks total, usually 1 => bounded tail.
// Distance math bit-identical to the 5x-verified f64-on-f32 expression.
__global__ __launch_bounds__(256) void fused_patch(
    const float* __restrict__ xyz, const float* __restrict__ pf,
    const float* __restrict__ pc,
    const unsigned short* __restrict__ w1p, const float* __restrict__ b1,
    const unsigned short* __restrict__ w2p, const float* __restrict__ b2,
    float* __restrict__ idx_out, float* __restrict__ out)
{
  const int tid  = threadIdx.x;
  const int lane = tid & 63;
  const int w    = tid >> 6;
  const int bs   = blockIdx.x;
  const int b    = bs >> 10;                  // S_ = 1024

  __shared__ int sidx[K_];
  __shared__ int swsum[4];
  __shared__ __align__(16) unsigned short As[K_][LDA];
  __shared__ __align__(16) unsigned short Hs[K_][LDH];

  const float* __restrict__ xb  = xyz + (size_t)b * N_ * 3;
  const float* __restrict__ pfb = pf  + (size_t)b * N_ * CSTEM;

  const float cen0 = pc[bs * 3 + 0];
  const float cen1 = pc[bs * 3 + 1];
  const float cen2 = pc[bs * 3 + 2];
  const double cx = (double)cen0, cy = (double)cen1, cz = (double)cen2;
  const double rr = 0.2 * 0.2;

  // ---- Ball query: 4096 pts/chunk, fully parallel test, ordered append ----
  int found = 0;
  for (int chunk = 0; chunk < N_; chunk += CHUNK) {
    const int i0 = chunk + tid * 16;
    unsigned mask = 0u;

#define TEST3(PX, PY, PZ, BIT) do {                                   \
      const double dx = (double)(PX) - cx;                            \
      const double dy = (double)(PY) - cy;                            \
      const double dz = (double)(PZ) - cz;                            \
      if ((dx * dx + dy * dy + dz * dz) <= rr) mask |= (1u << (BIT)); \
    } while (0)

    {   // points 0..7 (24 floats = 6 float4)
      const float4 q0 = *(const float4*)&xb[i0 * 3 + 0];
      const float4 q1 = *(const float4*)&xb[i0 * 3 + 4];
      const float4 q2 = *(const float4*)&xb[i0 * 3 + 8];
      const float4 q3 = *(const float4*)&xb[i0 * 3 + 12];
      const float4 q4 = *(const float4*)&xb[i0 * 3 + 16];
      const float4 q5 = *(const float4*)&xb[i0 * 3 + 20];
      TEST3(q0.x, q0.y, q0.z, 0);
      TEST3(q0.w, q1.x, q1.y, 1);
      TEST3(q1.z, q1.w, q2.x, 2);
      TEST3(q2.y, q2.z, q2.w, 3);
      TEST3(q3.x, q3.y, q3.z, 4);
      TEST3(q3.w, q4.x, q4.y, 5);
      TEST3(q4.z, q4.w, q5.x, 6);
      TEST3(q5.y, q5.z, q5.w, 7);
    }
    {   // points 8..15
      const float4 q0 = *(const float4*)&xb[i0 * 3 + 24];
      const float4 q1 = *(const float4*)&xb[i0 * 3 + 28];
      const float4 q2 = *(const float4*)&xb[i0 * 3 + 32];
      const float4 q3 = *(const float4*)&xb[i0 * 3 + 36];
      const float4 q4 = *(const float4*)&xb[i0 * 3 + 40];
      const float4 q5 = *(const float4*)&xb[i0 * 3 + 44];
      TEST3(q0.x, q0.y, q0.z, 8);
      TEST3(q0.w, q1.x, q1.y, 9);
      TEST3(q1.z, q1.w, q2.x, 10);
      TEST3(q2.y, q2.z, q2.w, 11);
      TEST3(q3.x, q3.y, q3.z, 12);
      TEST3(q3.w, q4.x, q4.y, 13);
      TEST3(q4.z, q4.w, q5.x, 14);
      TEST3(q5.y, q5.z, q5.w, 15);
    }
#undef TEST3

    const int cnt = __popc(mask);
    int incl = cnt;                     // wave-inclusive prefix of counts
    #pragma unroll
    for (int d = 1; d < 64; d <<= 1) {
      const int v = __shfl_up(incl, d);
      if (lane >= d) incl += v;
    }
    if (lane == 63) swsum[w] = incl;
    __syncthreads();

    int pos = found + (incl - cnt);
    #pragma unroll
    for (int v = 0; v < 4; ++v) if (v < w) pos += swsum[v];
    const int tot = swsum[0] + swsum[1] + swsum[2] + swsum[3];

    unsigned mm = mask;
    while (mm) {                        // ascending bit order = ascending index
      const int j = __builtin_ctz(mm);
      mm &= mm - 1;
      if (pos < K_) sidx[pos] = i0 + j;
      ++pos;
    }
    found += tot;
    __syncthreads();                    // append done; swsum reusable
    if (found >= K_) break;             // block-uniform
  }

  // ---- Fill (reference: pad with first found; if none found, index N-1)
  if (found == 0 && tid == 0) sidx[0] = N_ - 1;
  __syncthreads();
  if (tid < K_) {
    const int fill = sidx[0];
    const int v = (tid < found) ? sidx[tid] : fill;
    sidx[tid] = v;
    idx_out[(size_t)bs * K_ + tid] = (float)v;
  }
  __syncthreads();

  // ---- Weight fragments + biases (after ball phase to cap VGPR pressure)
  short8v w1f[3][2], w2f[4][2];
  #pragma unroll
  for (int ks = 0; ks < 3; ++ks)
    #pragma unroll
    for (int t = 0; t < 2; ++t)
      w1f[ks][t] = *(const short8v*)&w1p[((size_t)(ks * 8 + 2 * w + t) * 64 + lane) * 8];
  #pragma unroll
  for (int ks = 0; ks < 4; ++ks)
    #pragma unroll
    for (int t = 0; t < 2; ++t)
      w2f[ks][t] = *(const short8v*)&w2p[((size_t)(ks * 8 + 2 * w + t) * 64 + lane) * 8];
  const float bias1[2] = { b1[32 * w + (lane & 15)], b1[32 * w + 16 + (lane & 15)] };
  const float bias2[2] = { b2[32 * w + (lane & 15)], b2[32 * w + 16 + (lane & 15)] };

  // ---- Gather phase 1: features -> As[row][0..63] (8 threads per row)
  {
    const int row = tid >> 3, sub = tid & 7;
    const int r = sidx[row];
    const float4 f0 = *(const float4*)&pfb[(size_t)r * CSTEM + sub * 8];
    const float4 f1 = *(const float4*)&pfb[(size_t)r * CSTEM + sub * 8 + 4];
    unsigned short v[8];
    v[0] = f2bf(f0.x); v[1] = f2bf(f0.y); v[2] = f2bf(f0.z); v[3] = f2bf(f0.w);
    v[4] = f2bf(f1.x); v[5] = f2bf(f1.y); v[6] = f2bf(f1.z); v[7] = f2bf(f1.w);
    *(short8v*)&As[row][sub * 8] = *(const short8v*)v;
  }
  // ---- Gather phase 2: rel(3)+PE(24)+pad(5) -> As[row][64..95]
  {
    const int row = tid & 31, j = tid >> 5;
    const int r = sidx[row];
    float rel[3];
    rel[0] = xb[r * 3 + 0] - cen0;
    rel[1] = xb[r * 3 + 1] - cen1;
    rel[2] = xb[r * 3 + 2] - cen2;
    #pragma unroll
    for (int cc = 0; cc < 4; ++cc) {
      const int c = 64 + 4 * j + cc;
      float val;
      if (c < 67) val = rel[c - 64];
      else if (c < 91) {
        const int q = c - 67, d = q >> 3, rbit = q & 7, band = rbit & 3;
        const float ang = rel[d] * ((float)(1 << band) * 3.14159265358979323846f);
        val = (rbit < 4) ? __sinf(ang) : __cosf(ang);  // err << bf16 rounding
      } else val = 0.f;
      As[row][c] = f2bf(val);
    }
  }
  __syncthreads();

  // ---- Layer 1: 32x96 @ 96x128 (A from LDS, B from registers)
  f32x4 acc[2][2] = {};
  #pragma unroll
  for (int ks = 0; ks < 3; ++ks) {
    const int k0 = ks * 32 + (lane >> 4) * 8;
    const short8v a0 = *(const short8v*)&As[(lane & 15)][k0];
    const short8v a1 = *(const short8v*)&As[16 + (lane & 15)][k0];
    acc[0][0] = __builtin_amdgcn_mfma_f32_16x16x32_bf16(a0, w1f[ks][0], acc[0][0], 0, 0, 0);
    acc[0][1] = __builtin_amdgcn_mfma_f32_16x16x32_bf16(a0, w1f[ks][1], acc[0][1], 0, 0, 0);
    acc[1][0] = __builtin_amdgcn_mfma_f32_16x16x32_bf16(a1, w1f[ks][0], acc[1][0], 0, 0, 0);
    acc[1][1] = __builtin_amdgcn_mfma_f32_16x16x32_bf16(a1, w1f[ks][1], acc[1][1], 0, 0, 0);
  }
  #pragma unroll
  for (int rt = 0; rt < 2; ++rt)
    #pragma unroll
    for (int t = 0; t < 2; ++t)
      #pragma unroll
      for (int reg = 0; reg < 4; ++reg) {
        const float h = fmaxf(acc[rt][t][reg] + bias1[t], 0.f);
        const int row = 16 * rt + (lane >> 4) * 4 + reg;
        const int col = 32 * w + 16 * t + (lane & 15);
        Hs[row][col] = f2bf(h);
      }
  __syncthreads();

  // ---- Layer 2: 32x128 @ 128x128 + max over rows
  f32x4 acc2[2][2] = {};
  #pragma unroll
  for (int ks = 0; ks < 4; ++ks) {
    const int k0 = ks * 32 + (lane >> 4) * 8;
    const short8v a0 = *(const short8v*)&Hs[(lane & 15)][k0];
    const short8v a1 = *(const short8v*)&Hs[16 + (lane & 15)][k0];
    acc2[0][0] = __builtin_amdgcn_mfma_f32_16x16x32_bf16(a0, w2f[ks][0], acc2[0][0], 0, 0, 0);
    acc2[0][1] = __builtin_amdgcn_mfma_f32_16x16x32_bf16(a0, w2f[ks][1], acc2[0][1], 0, 0, 0);
    acc2[1][0] = __builtin_amdgcn_mfma_f32_16x16x32_bf16(a1, w2f[ks][0], acc2[1][0], 0, 0, 0);
    acc2[1][1] = __builtin_amdgcn_mfma_f32_16x16x32_bf16(a1, w2f[ks][1], acc2[1][1], 0, 0, 0);
  }
  float m0 = -3.4e38f, m1 = -3.4e38f;
  #pragma unroll
  for (int rt = 0; rt < 2; ++rt)
    #pragma unroll
    for (int reg = 0; reg < 4; ++reg) {
      m0 = fmaxf(m0, acc2[rt][0][reg]);
      m1 = fmaxf(m1, acc2[rt][1][reg]);
    }
  m0 += bias2[0];
  m1 += bias2[1];
  m0 = fmaxf(m0, __shfl_xor(m0, 16));
  m0 = fmaxf(m0, __shfl_xor(m0, 32));
  m1 = fmaxf(m1, __shfl_xor(m1, 16));
  m1 = fmaxf(m1, __shfl_xor(m1, 32));
  if (lane < 16) {
    out[(size_t)bs * CPATCH + 32 * w + lane]      = m0;
    out[(size_t)bs * CPATCH + 32 * w + 16 + lane] = m1;
  }
}

extern "C" void kernel_launch(void* const* d_in, const int* in_sizes, int n_in,
                              void* d_out, int out_size, void* d_ws, size_t ws_size,
                              hipStream_t stream) {
  const float* xyz = (const float*)d_in[0];
  const float* pf  = (const float*)d_in[1];
  const float* pc  = (const float*)d_in[2];
  const float* w1  = (const float*)d_in[3];
  const float* b1  = (const float*)d_in[4];
  const float* w2  = (const float*)d_in[5];
  const float* b2  = (const float*)d_in[6];

  float* out     = (float*)d_out;
  float* idx_out = out + (size_t)B_ * S_ * CPATCH;

  unsigned short* w1p = (unsigned short*)d_ws;
  unsigned short* w2p = w1p + 96 * 128;

  pack_weights<<<14, 256, 0, stream>>>(w1, w2, w1p, w2p);
  fused_patch<<<B_ * S_, 256, 0, stream>>>(xyz, pf, pc, w1p, b1, w2p, b2,
                                           idx_out, out);
}

// Round 7
// 53.602 us; speedup vs baseline: 1.1536x; 1.1498x over previous
//
#include <hip/hip_runtime.h>
#include <hip/hip_bf16.h>

#define B_ 8
#define N_ 16384
#define S_ 1024
#define K_ 32
#define CSTEM 64
#define CPATCH 128
#define INDIM 91
#define LDA 104     // LDS row stride (bf16) for A tile
#define LDH 136     // LDS row stride (bf16) for h1 tile
#define NQ 4        // queries (patches) per block
#define CHUNK 2048  // ball chunk: 256 threads x 8 pts

typedef __attribute__((ext_vector_type(8))) short short8v;  // 8 bf16 = 4 VGPRs
typedef __attribute__((ext_vector_type(4))) float f32x4;

static __device__ __forceinline__ unsigned short f2bf(float f) {
  union { float f; unsigned int u; } v; v.f = f;
  return (unsigned short)((v.u + 0x7FFFu + ((v.u >> 16) & 1u)) >> 16);  // RNE
}

// -------- Kernel 0: pack w1/w2 into MFMA B-fragment order (bf16) --------
__global__ __launch_bounds__(256) void pack_weights(
    const float* __restrict__ w1, const float* __restrict__ w2,
    unsigned short* __restrict__ w1p, unsigned short* __restrict__ w2p)
{
  const int id = blockIdx.x * 256 + threadIdx.x;
  if (id < 3 * 8 * 64) {                       // w1: K padded 91->96 (3 ksteps)
    const int l = id & 63, ct = (id >> 6) & 7, ks = id >> 9;
    const int col = 16 * ct + (l & 15);
    const int kb = 32 * ks + (l >> 4) * 8;
    unsigned short v[8];
    #pragma unroll
    for (int j = 0; j < 8; ++j) {
      const int k = kb + j;
      v[j] = (k < INDIM) ? f2bf(w1[k * CPATCH + col]) : (unsigned short)0;
    }
    *(short8v*)&w1p[(size_t)id * 8] = *(const short8v*)v;
  } else if (id < 3 * 8 * 64 + 4 * 8 * 64) {   // w2: 4 ksteps
    const int id2 = id - 3 * 8 * 64;
    const int l = id2 & 63, ct = (id2 >> 6) & 7, ks = id2 >> 9;
    const int col = 16 * ct + (l & 15);
    const int kb = 32 * ks + (l >> 4) * 8;
    unsigned short v[8];
    #pragma unroll
    for (int j = 0; j < 8; ++j) v[j] = f2bf(w2[(kb + j) * CPATCH + col]);
    *(short8v*)&w2p[(size_t)id2 * 8] = *(const short8v*)v;
  }
}

// -------- Fused: joint-4 ball query + batched gather + MFMA MLP + max ------
// One block = 4 consecutive patches (same batch). Each loaded point is tested
// against 4 centers (loads amortized 4x). f32 distance test with f64 recheck
// in a +-1e-5 band around r^2 (f32 error bound ~7e-7) => decisions provably
// identical to the 6x-verified f64 expression.
__global__ __launch_bounds__(256) void fused_patch(
    const float* __restrict__ xyz, const float* __restrict__ pf,
    const float* __restrict__ pc,
    const unsigned short* __restrict__ w1p, const float* __restrict__ b1,
    const unsigned short* __restrict__ w2p, const float* __restrict__ b2,
    float* __restrict__ idx_out, float* __restrict__ out)
{
  const int tid  = threadIdx.x;
  const int lane = tid & 63;
  const int w    = tid >> 6;
  const int bs0  = blockIdx.x * NQ;            // 4 consecutive patches
  const int b    = bs0 >> 10;                  // S_ = 1024, NQ | S_

  __shared__ float scen[3 * NQ];
  __shared__ int   sidx[NQ][K_];
  __shared__ float sxyz[NQ][K_][3];
  __shared__ int   swsum[4][NQ];
  __shared__ int   sfound[NQ];
  __shared__ __align__(16) unsigned short As[NQ * K_][LDA];
  __shared__ __align__(16) unsigned short Hs[K_][LDH];

  const float* __restrict__ xb  = xyz + (size_t)b * N_ * 3;
  const float* __restrict__ pfb = pf  + (size_t)b * N_ * CSTEM;

  if (tid < 3 * NQ) scen[tid] = pc[bs0 * 3 + tid];
  __syncthreads();

  float cxf[NQ], cyf[NQ], czf[NQ];
  #pragma unroll
  for (int q = 0; q < NQ; ++q) {
    cxf[q] = scen[q * 3 + 0];
    cyf[q] = scen[q * 3 + 1];
    czf[q] = scen[q * 3 + 2];
  }
  const double rr = 0.2 * 0.2;

  // ---- Ball query: 2048 pts/chunk, 4 queries share every loaded point ----
  int found[NQ] = {0, 0, 0, 0};
  const unsigned long long lower = (1ull << lane) - 1ull;

  for (int chunk = 0; chunk < N_; chunk += CHUNK) {
    const int i0 = chunk + tid * 8;
    float px[8], py[8], pz[8];
    {
      const float4 v0 = *(const float4*)&xb[i0 * 3 + 0];
      const float4 v1 = *(const float4*)&xb[i0 * 3 + 4];
      const float4 v2 = *(const float4*)&xb[i0 * 3 + 8];
      const float4 v3 = *(const float4*)&xb[i0 * 3 + 12];
      const float4 v4 = *(const float4*)&xb[i0 * 3 + 16];
      const float4 v5 = *(const float4*)&xb[i0 * 3 + 20];
      px[0] = v0.x; py[0] = v0.y; pz[0] = v0.z;
      px[1] = v0.w; py[1] = v1.x; pz[1] = v1.y;
      px[2] = v1.z; py[2] = v1.w; pz[2] = v2.x;
      px[3] = v2.y; py[3] = v2.z; pz[3] = v2.w;
      px[4] = v3.x; py[4] = v3.y; pz[4] = v3.z;
      px[5] = v3.w; py[5] = v4.x; pz[5] = v4.y;
      px[6] = v4.z; py[6] = v4.w; pz[6] = v5.x;
      px[7] = v5.y; py[7] = v5.z; pz[7] = v5.w;
    }

    unsigned mask[NQ];
    #pragma unroll
    for (int q = 0; q < NQ; ++q) {
      mask[q] = 0u;
      if (found[q] < K_) {
        #pragma unroll
        for (int p = 0; p < 8; ++p) {
          const float dxf = px[p] - cxf[q];
          const float dyf = py[p] - cyf[q];
          const float dzf = pz[p] - czf[q];
          const float d2f = fmaf(dxf, dxf, fmaf(dyf, dyf, dzf * dzf));
          bool in;
          if (fabsf(d2f - 0.04f) <= 1e-5f) {      // rare: exact f64 recheck
            const double dx = (double)px[p] - (double)cxf[q];
            const double dy = (double)py[p] - (double)cyf[q];
            const double dz = (double)pz[p] - (double)czf[q];
            in = (dx * dx + dy * dy + dz * dz) <= rr;
          } else {
            in = (d2f < 0.04f);
          }
          if (in) mask[q] |= (1u << p);
        }
      }
    }

    // packed dual prefix scans (counts <=8, inclusive sums <=512 => 16b fields)
    const int c0 = __popc(mask[0]), c1 = __popc(mask[1]);
    const int c2 = __popc(mask[2]), c3 = __popc(mask[3]);
    unsigned pA = (unsigned)c0 | ((unsigned)c1 << 16);
    unsigned pB = (unsigned)c2 | ((unsigned)c3 << 16);
    #pragma unroll
    for (int d = 1; d < 64; d <<= 1) {
      const unsigned vA = (unsigned)__shfl_up((int)pA, d);
      const unsigned vB = (unsigned)__shfl_up((int)pB, d);
      if (lane >= d) { pA += vA; pB += vB; }
    }
    int incl[NQ];
    incl[0] = pA & 0xFFFF; incl[1] = pA >> 16;
    incl[2] = pB & 0xFFFF; incl[3] = pB >> 16;
    if (lane == 63) {
      #pragma unroll
      for (int q = 0; q < NQ; ++q) swsum[w][q] = incl[q];
    }
    __syncthreads();

    int cnt[NQ] = {c0, c1, c2, c3};
    #pragma unroll
    for (int q = 0; q < NQ; ++q) {
      if (found[q] < K_) {
        int pos = found[q] + (incl[q] - cnt[q]);
        #pragma unroll
        for (int v = 0; v < 4; ++v) if (v < w) pos += swsum[v][q];
        #pragma unroll
        for (int p = 0; p < 8; ++p) {
          if (mask[q] & (1u << p)) {
            if (pos < K_) {
              sidx[q][pos] = i0 + p;
              sxyz[q][pos][0] = px[p];
              sxyz[q][pos][1] = py[p];
              sxyz[q][pos][2] = pz[p];
            }
            ++pos;
          }
        }
        found[q] += swsum[0][q] + swsum[1][q] + swsum[2][q] + swsum[3][q];
      }
    }
    __syncthreads();                             // swsum/sidx reuse
    if (found[0] >= K_ && found[1] >= K_ && found[2] >= K_ && found[3] >= K_)
      break;                                     // block-uniform
  }

  // ---- Fill (reference: pad with first found; none found -> index N-1) ----
  if (tid == 0) {
    #pragma unroll
    for (int q = 0; q < NQ; ++q) {
      sfound[q] = found[q];
      if (found[q] == 0) {
        sidx[q][0] = N_ - 1;
        sxyz[q][0][0] = xb[(N_ - 1) * 3 + 0];
        sxyz[q][0][1] = xb[(N_ - 1) * 3 + 1];
        sxyz[q][0][2] = xb[(N_ - 1) * 3 + 2];
      }
    }
  }
  __syncthreads();
  if (tid < NQ * K_) {
    const int q = tid >> 5, j = tid & 31;
    const int fq = sfound[q];
    const int v   = (j < fq && fq > 0) ? sidx[q][j]    : sidx[q][0];
    const float x = (j < fq && fq > 0) ? sxyz[q][j][0] : sxyz[q][0][0];
    const float y = (j < fq && fq > 0) ? sxyz[q][j][1] : sxyz[q][0][1];
    const float z = (j < fq && fq > 0) ? sxyz[q][j][2] : sxyz[q][0][2];
    sidx[q][j] = v;
    sxyz[q][j][0] = x; sxyz[q][j][1] = y; sxyz[q][j][2] = z;
    idx_out[(size_t)bs0 * K_ + tid] = (float)v;
  }
  __syncthreads();

  // ---- Weight fragments + biases (loaded once, used for NQ patches) ----
  short8v w1f[3][2], w2f[4][2];
  #pragma unroll
  for (int ks = 0; ks < 3; ++ks)
    #pragma unroll
    for (int t = 0; t < 2; ++t)
      w1f[ks][t] = *(const short8v*)&w1p[((size_t)(ks * 8 + 2 * w + t) * 64 + lane) * 8];
  #pragma unroll
  for (int ks = 0; ks < 4; ++ks)
    #pragma unroll
    for (int t = 0; t < 2; ++t)
      w2f[ks][t] = *(const short8v*)&w2p[((size_t)(ks * 8 + 2 * w + t) * 64 + lane) * 8];
  const float bias1[2] = { b1[32 * w + (lane & 15)], b1[32 * w + 16 + (lane & 15)] };
  const float bias2[2] = { b2[32 * w + (lane & 15)], b2[32 * w + 16 + (lane & 15)] };

  // ---- Batched gather: all 4 patches staged before any MFMA ----
  {
    const int row = tid >> 3, sub = tid & 7;     // feature loads, 8 thr/row
    #pragma unroll
    for (int q = 0; q < NQ; ++q) {
      const int r = sidx[q][row];
      const float4 f0 = *(const float4*)&pfb[(size_t)r * CSTEM + sub * 8];
      const float4 f1 = *(const float4*)&pfb[(size_t)r * CSTEM + sub * 8 + 4];
      unsigned short v[8];
      v[0] = f2bf(f0.x); v[1] = f2bf(f0.y); v[2] = f2bf(f0.z); v[3] = f2bf(f0.w);
      v[4] = f2bf(f1.x); v[5] = f2bf(f1.y); v[6] = f2bf(f1.z); v[7] = f2bf(f1.w);
      *(short8v*)&As[q * K_ + row][sub * 8] = *(const short8v*)v;
    }
  }
  {
    const int row = tid & 31, j = tid >> 5;      // rel+PE, 8 thr/row x 4 cols
    #pragma unroll
    for (int q = 0; q < NQ; ++q) {
      const float r0 = sxyz[q][row][0] - cxf[q];
      const float r1 = sxyz[q][row][1] - cyf[q];
      const float r2 = sxyz[q][row][2] - czf[q];
      #pragma unroll
      for (int cc = 0; cc < 4; ++cc) {
        const int c = 64 + 4 * j + cc;
        float val;
        if (c < 67) val = (c == 64) ? r0 : ((c == 65) ? r1 : r2);
        else if (c < 91) {
          const int qq = c - 67, d = qq >> 3, rbit = qq & 7, band = rbit & 3;
          const float rel = (d == 0) ? r0 : ((d == 1) ? r1 : r2);
          const float ang = rel * ((float)(1 << band) * 3.14159265358979323846f);
          val = (rbit < 4) ? __sinf(ang) : __cosf(ang);
        } else val = 0.f;
        As[q * K_ + row][c] = f2bf(val);
      }
    }
  }
  __syncthreads();

  // ---- Per patch: L1 MFMA -> relu -> Hs -> L2 MFMA -> column max ----
  #pragma unroll 1
  for (int q = 0; q < NQ; ++q) {
    f32x4 acc[2][2] = {};
    #pragma unroll
    for (int ks = 0; ks < 3; ++ks) {
      const int k0 = ks * 32 + (lane >> 4) * 8;
      const short8v a0 = *(const short8v*)&As[q * K_ + (lane & 15)][k0];
      const short8v a1 = *(const short8v*)&As[q * K_ + 16 + (lane & 15)][k0];
      acc[0][0] = __builtin_amdgcn_mfma_f32_16x16x32_bf16(a0, w1f[ks][0], acc[0][0], 0, 0, 0);
      acc[0][1] = __builtin_amdgcn_mfma_f32_16x16x32_bf16(a0, w1f[ks][1], acc[0][1], 0, 0, 0);
      acc[1][0] = __builtin_amdgcn_mfma_f32_16x16x32_bf16(a1, w1f[ks][0], acc[1][0], 0, 0, 0);
      acc[1][1] = __builtin_amdgcn_mfma_f32_16x16x32_bf16(a1, w1f[ks][1], acc[1][1], 0, 0, 0);
    }
    #pragma unroll
    for (int rt = 0; rt < 2; ++rt)
      #pragma unroll
      for (int t = 0; t < 2; ++t)
        #pragma unroll
        for (int reg = 0; reg < 4; ++reg) {
          const float h = fmaxf(acc[rt][t][reg] + bias1[t], 0.f);
          const int row = 16 * rt + (lane >> 4) * 4 + reg;
          const int col = 32 * w + 16 * t + (lane & 15);
          Hs[row][col] = f2bf(h);
        }
    __syncthreads();

    f32x4 acc2[2][2] = {};
    #pragma unroll
    for (int ks = 0; ks < 4; ++ks) {
      const int k0 = ks * 32 + (lane >> 4) * 8;
      const short8v a0 = *(const short8v*)&Hs[(lane & 15)][k0];
      const short8v a1 = *(const short8v*)&Hs[16 + (lane & 15)][k0];
      acc2[0][0] = __builtin_amdgcn_mfma_f32_16x16x32_bf16(a0, w2f[ks][0], acc2[0][0], 0, 0, 0);
      acc2[0][1] = __builtin_amdgcn_mfma_f32_16x16x32_bf16(a0, w2f[ks][1], acc2[0][1], 0, 0, 0);
      acc2[1][0] = __builtin_amdgcn_mfma_f32_16x16x32_bf16(a1, w2f[ks][0], acc2[1][0], 0, 0, 0);
      acc2[1][1] = __builtin_amdgcn_mfma_f32_16x16x32_bf16(a1, w2f[ks][1], acc2[1][1], 0, 0, 0);
    }
    float m0 = -3.4e38f, m1 = -3.4e38f;
    #pragma unroll
    for (int rt = 0; rt < 2; ++rt)
      #pragma unroll
      for (int reg = 0; reg < 4; ++reg) {
        m0 = fmaxf(m0, acc2[rt][0][reg]);
        m1 = fmaxf(m1, acc2[rt][1][reg]);
      }
    m0 += bias2[0];
    m1 += bias2[1];
    m0 = fmaxf(m0, __shfl_xor(m0, 16));
    m0 = fmaxf(m0, __shfl_xor(m0, 32));
    m1 = fmaxf(m1, __shfl_xor(m1, 16));
    m1 = fmaxf(m1, __shfl_xor(m1, 32));
    if (lane < 16) {
      out[(size_t)(bs0 + q) * CPATCH + 32 * w + lane]      = m0;
      out[(size_t)(bs0 + q) * CPATCH + 32 * w + 16 + lane] = m1;
    }
    __syncthreads();                             // Hs reuse next patch
  }
}

extern "C" void kernel_launch(void* const* d_in, const int* in_sizes, int n_in,
                              void* d_out, int out_size, void* d_ws, size_t ws_size,
                              hipStream_t stream) {
  const float* xyz = (const float*)d_in[0];
  const float* pf  = (const float*)d_in[1];
  const float* pc  = (const float*)d_in[2];
  const float* w1  = (const float*)d_in[3];
  const float* b1  = (const float*)d_in[4];
  const float* w2  = (const float*)d_in[5];
  const float* b2  = (const float*)d_in[6];

  float* out     = (float*)d_out;
  float* idx_out = out + (size_t)B_ * S_ * CPATCH;

  unsigned short* w1p = (unsigned short*)d_ws;
  unsigned short* w2p = w1p + 96 * 128;

  pack_weights<<<14, 256, 0, stream>>>(w1, w2, w1p, w2p);
  fused_patch<<<B_ * S_ / NQ, 256, 0, stream>>>(xyz, pf, pc, w1p, b1, w2p, b2,
                                                idx_out, out);
}